// Round 9
// baseline (1882.692 us; speedup 1.0000x reference)
//
#include <hip/hip_runtime.h>
#include <stdint.h>
#include <stddef.h>

#define NEGF (-1.0e30f)

typedef __attribute__((ext_vector_type(2))) _Float16 half2_t;
typedef uint32_t u32x16 __attribute__((ext_vector_type(16)));

constexpr int Bn = 32;
constexpr int Tn = 2000;
constexpr int Cn = 256;
constexpr int Un = 200;
constexpr int Sn = 2 * Un + 1;  // 401 extended states
constexpr float Kn = 4096.0f;   // den normalization target

// f16 pair dot with fp32 accumulate: c += a.x*b.x + a.y*b.y
__device__ __forceinline__ float fdot2f(uint32_t a, uint32_t b, float c) {
  half2_t ha = __builtin_bit_cast(half2_t, a);
  half2_t hb = __builtin_bit_cast(half2_t, b);
#if __has_builtin(__builtin_amdgcn_fdot2)
  return __builtin_amdgcn_fdot2(ha, hb, c, false);
#else
  return c + (float)ha.x * (float)hb.x + (float)ha.y * (float)hb.y;
#endif
}

template <int CTRL>
__device__ __forceinline__ float dppf(float x) {
#if __has_builtin(__builtin_amdgcn_update_dpp)
  int xi = __builtin_bit_cast(int, x);
  int y = __builtin_amdgcn_update_dpp(0, xi, CTRL, 0xF, 0xF, false);
  return __builtin_bit_cast(float, y);
#else
  return x;
#endif
}
#define dpp_x1(v) dppf<0xB1>(v)   // quad_perm(1,0,3,2): lane ^ 1
#define dpp_x2(v) dppf<0x4E>(v)   // quad_perm(2,3,0,1): lane ^ 2
#define dpp_x7(v) dppf<0x141>(v)  // row_half_mirror:    lane ^ 7

__device__ __forceinline__ uint32_t packe(float a, float b) {
  half2_t h;
  h.x = (_Float16)a;
  h.y = (_Float16)b;
  return __builtin_bit_cast(uint32_t, h);
}

__device__ __forceinline__ float lse3(float a, float b, float c) {
  float m = fmaxf(fmaxf(a, b), c);
  return m + __logf(__expf(a - m) + __expf(b - m) + __expf(c - m));
}

__device__ __forceinline__ int clampi(int v, int lo, int hi) {
  return v < lo ? lo : (v > hi ? hi : v);
}

// Barrier WITHOUT the vmcnt(0) drain __syncthreads() emits: only LDS
// (lgkmcnt) must drain for cross-wave ds_write visibility; the compiler
// still inserts counted vmcnt(N) before each prefetch USE.
__device__ __forceinline__ void barrier_nodrain() {
  asm volatile("s_waitcnt lgkmcnt(0)" ::: "memory");
  __builtin_amdgcn_s_barrier();
  asm volatile("" ::: "memory");
}

// ============================================================================
// ROUND-11: two batches per block (ILP latency fill).
// Ledger: R1 den=1188 cyc/step (issue ~460), num=960 (issue ~200) -> both
// ~60-75% exposed latency. R2: extra LOCKSTEP waves don't fill it (barrier
// co-stall). R8: den+num co-residency can't win (they already overlap on
// separate CUs; fusing only adds contention -> 1603 cyc/step). Fix: give each
// wave an INDEPENDENT twin of its own latency chain: process batches (2i,2i+1)
// in one block. den: shared E (trans is batch-invariant), 2 alpha LDS bufs,
// dual accumulators; num: dual state/emission sets. Loop runs to max(LA,LB);
// freeze = keep re-writing the remembered last value (den: pv f16; num: the
// already-loaded old alpha x), G/state updates gated by t < L.
// Blocks: [0,16) den pairs, [16,32) num pairs; 256 thr, 1 wave/SIMD.
// ============================================================================

__global__ __launch_bounds__(256)
__attribute__((amdgpu_waves_per_eu(1, 1)))
void fwd_kernel(
    const float* __restrict__ logp, const int* __restrict__ targets,
    const int* __restrict__ in_lens, const int* __restrict__ tgt_lens,
    const float* __restrict__ trans, const float* __restrict__ start,
    float* __restrict__ ws) {
  const int tid = threadIdx.x;
  const int bid = blockIdx.x;

  if (bid < 16) {
    // ==================== den pair (batches 2*bid, 2*bid+1) ====================
    const int bA = 2 * bid, bB = bA + 1;
    const int LA = clampi(in_lens[bA], Sn, Tn);
    const int LB = clampi(in_lens[bB], Sn, Tn);
    const int Lm = LA > LB ? LA : LB;
    const int q = tid & 7;
    const int u = tid >> 3;
    const int jw = u + 32 * q;  // column this lane owns after the reduce

    // [batch][dbuf][8 chunks x 80B]; 80B stride = conflict-free b128 reads
    __shared__ __align__(16) char eaLDS[2 * 1280];
    __shared__ float sredA[4], sredB[4];

    const float* trow = trans;
#define EP(c, m) packe(__expf(trow[(32 * q + 2 * (m)) * Cn + (c)]), \
                       __expf(trow[(32 * q + 2 * (m) + 1) * Cn + (c)]))
#define MKCOL(c)                                                          \
  (u32x16){EP(c, 0),  EP(c, 1),  EP(c, 2),  EP(c, 3),  EP(c, 4),          \
           EP(c, 5),  EP(c, 6),  EP(c, 7),  EP(c, 8),  EP(c, 9),          \
           EP(c, 10), EP(c, 11), EP(c, 12), EP(c, 13), EP(c, 14), EP(c, 15)}
    u32x16 E0 = MKCOL(u + 0);
    u32x16 E1 = MKCOL(u + 32);
    u32x16 E2 = MKCOL(u + 64);
    u32x16 E3 = MKCOL(u + 96);
    u32x16 E4 = MKCOL(u + 128);
    u32x16 E5 = MKCOL(u + 160);
    u32x16 E6 = MKCOL(u + 192);
    u32x16 E7 = MKCOL(u + 224);
#undef MKCOL
#undef EP

    const float* lpA = logp + (size_t)bA * Tn * Cn;
    const float* lpB = logp + (size_t)bB * Tn * Cn;
    const char* rbA = eaLDS + 80 * q;
    const char* rbB = eaLDS + 1280 + 80 * q;
    char* wpA = eaLDS + 80 * q + 2 * u;
    char* wpB = eaLDS + 1280 + 80 * q + 2 * u;

    // t = 0: stored = K*exp(start + lp0); pv remembers last written (freeze src)
    float GA = -__logf(Kn), GB = -__logf(Kn);
    _Float16 pvA = (_Float16)(Kn * __expf(start[jw] + lpA[jw]));
    _Float16 pvB = (_Float16)(Kn * __expf(start[jw] + lpB[jw]));
    *(_Float16*)wpA = pvA;
    *(_Float16*)wpB = pvB;
    // 2-deep emission prefetch (L >= Sn = 401 for both)
    float lpA0 = lpA[Cn + jw], lpA1 = lpA[(size_t)2 * Cn + jw];
    float lpB0 = lpB[Cn + jw], lpB1 = lpB[(size_t)2 * Cn + jw];
    __syncthreads();

    const uint32_t ONE2 = 0x3C003C00u;  // f16 (1.0, 1.0)
    const bool q4 = (q & 4) != 0, q2 = (q & 2) != 0, q1 = (q & 1) != 0;

    for (int t = 1; t < Lm; ++t) {
      const int pr = (t - 1) & 1, pw = t & 1;
      const float pA = __expf(lpA0), pB = __expf(lpB0);
      lpA0 = lpA1;
      lpB0 = lpB1;
      const int tpre = (t + 2 < Lm) ? t + 2 : Lm - 1;
      lpA1 = lpA[(size_t)tpre * Cn + jw];
      lpB1 = lpB[(size_t)tpre * Cn + jw];

      const uint4* eapA = (const uint4*)(rbA + pr * 640);
      const uint4* eapB = (const uint4*)(rbB + pr * 640);
      float a0 = 0.f, a1 = 0.f, a2 = 0.f, a3 = 0.f;
      float a4 = 0.f, a5 = 0.f, a6 = 0.f, a7 = 0.f;
      float c0 = 0.f, c1 = 0.f, c2 = 0.f, c3 = 0.f;
      float c4 = 0.f, c5 = 0.f, c6 = 0.f, c7 = 0.f;
      half2_t zpA = {(_Float16)0.f, (_Float16)0.f};
      half2_t zpB = {(_Float16)0.f, (_Float16)0.f};
#define B2(x) __builtin_bit_cast(half2_t, x)
#define DOT8A(idx, ev)              \
  a0 = fdot2f(E0[idx], ev, a0);     \
  a1 = fdot2f(E1[idx], ev, a1);     \
  a2 = fdot2f(E2[idx], ev, a2);     \
  a3 = fdot2f(E3[idx], ev, a3);     \
  a4 = fdot2f(E4[idx], ev, a4);     \
  a5 = fdot2f(E5[idx], ev, a5);     \
  a6 = fdot2f(E6[idx], ev, a6);     \
  a7 = fdot2f(E7[idx], ev, a7);
#define DOT8B(idx, ev)              \
  c0 = fdot2f(E0[idx], ev, c0);     \
  c1 = fdot2f(E1[idx], ev, c1);     \
  c2 = fdot2f(E2[idx], ev, c2);     \
  c3 = fdot2f(E3[idx], ev, c3);     \
  c4 = fdot2f(E4[idx], ev, c4);     \
  c5 = fdot2f(E5[idx], ev, c5);     \
  c6 = fdot2f(E6[idx], ev, c6);     \
  c7 = fdot2f(E7[idx], ev, c7);
#define DOTQA(m4)                                                     \
  {                                                                   \
    const uint4 e4 = eapA[m4];                                        \
    DOT8A(4 * (m4) + 0, e4.x)                                         \
    DOT8A(4 * (m4) + 1, e4.y)                                         \
    DOT8A(4 * (m4) + 2, e4.z)                                         \
    DOT8A(4 * (m4) + 3, e4.w)                                         \
    zpA = zpA + ((B2(e4.x) + B2(e4.y)) + (B2(e4.z) + B2(e4.w)));      \
  }
#define DOTQB(m4)                                                     \
  {                                                                   \
    const uint4 e4 = eapB[m4];                                        \
    DOT8B(4 * (m4) + 0, e4.x)                                         \
    DOT8B(4 * (m4) + 1, e4.y)                                         \
    DOT8B(4 * (m4) + 2, e4.z)                                         \
    DOT8B(4 * (m4) + 3, e4.w)                                         \
    zpB = zpB + ((B2(e4.x) + B2(e4.y)) + (B2(e4.z) + B2(e4.w)));      \
  }
      DOTQA(0)
      DOTQB(0)
      DOTQA(1)
      DOTQB(1)
      DOTQA(2)
      DOTQB(2)
      DOTQA(3)
      DOTQB(3)
#undef DOTQA
#undef DOTQB
#undef DOT8A
#undef DOT8B
#undef B2

      // Z reduces (independent chains, interleave)
      float zcA = fdot2f(ONE2, __builtin_bit_cast(uint32_t, zpA), 0.f);
      float zcB = fdot2f(ONE2, __builtin_bit_cast(uint32_t, zpB), 0.f);
      zcA += dpp_x1(zcA);
      zcB += dpp_x1(zcB);
      zcA += dpp_x2(zcA);
      zcB += dpp_x2(zcB);
      zcA += dpp_x7(zcA);
      zcB += dpp_x7(zcB);

      // column reduces over the 8-lane q-group: give/keep halving exchange
      float g, t0, t1, t2, t3, w0, w1, sA, sB;
      g = q4 ? a0 : a4;  t0 = (q4 ? a4 : a0) + dpp_x7(g);
      g = q4 ? a1 : a5;  t1 = (q4 ? a5 : a1) + dpp_x7(g);
      g = q4 ? a2 : a6;  t2 = (q4 ? a6 : a2) + dpp_x7(g);
      g = q4 ? a3 : a7;  t3 = (q4 ? a7 : a3) + dpp_x7(g);
      g = q2 ? t0 : t2;  w0 = (q2 ? t2 : t0) + dpp_x2(g);
      g = q2 ? t1 : t3;  w1 = (q2 ? t3 : t1) + dpp_x2(g);
      g = q1 ? w0 : w1;  sA = (q1 ? w1 : w0) + dpp_x1(g);
      g = q4 ? c0 : c4;  t0 = (q4 ? c4 : c0) + dpp_x7(g);
      g = q4 ? c1 : c5;  t1 = (q4 ? c5 : c1) + dpp_x7(g);
      g = q4 ? c2 : c6;  t2 = (q4 ? c6 : c2) + dpp_x7(g);
      g = q4 ? c3 : c7;  t3 = (q4 ? c7 : c3) + dpp_x7(g);
      g = q2 ? t0 : t2;  w0 = (q2 ? t2 : t0) + dpp_x2(g);
      g = q2 ? t1 : t3;  w1 = (q2 ? t3 : t1) + dpp_x2(g);
      g = q1 ? w0 : w1;  sB = (q1 ? w1 : w0) + dpp_x1(g);

      const float invZA = Kn * __frcp_rn(zcA);
      const float invZB = Kn * __frcp_rn(zcB);
      if (t < LA) {
        GA -= __logf(invZA);
        pvA = (_Float16)(sA * pA * invZA);
      }
      if (t < LB) {
        GB -= __logf(invZB);
        pvB = (_Float16)(sB * pB * invZB);
      }
      *(_Float16*)(wpA + pw * 640) = pvA;  // frozen batch: rewrite last value
      *(_Float16*)(wpB + pw * 640) = pvB;
      barrier_nodrain();
    }

    // den[b] = G + log(rowsum(alpha_final)); both buffers hold frozen finals
    {
      const int pL = (Lm - 1) & 1;
      const char* fA = eaLDS + pL * 640;
      const char* fB = eaLDS + 1280 + pL * 640;
      float eA = (float)(*(const _Float16*)(fA + 80 * (tid >> 5) + 2 * (tid & 31)));
      float eB = (float)(*(const _Float16*)(fB + 80 * (tid >> 5) + 2 * (tid & 31)));
#pragma unroll
      for (int off = 32; off >= 1; off >>= 1) {
        eA += __shfl_xor(eA, off, 64);
        eB += __shfl_xor(eB, off, 64);
      }
      const int lane = tid & 63, wid = tid >> 6;
      if (lane == 0) {
        sredA[wid] = eA;
        sredB[wid] = eB;
      }
      __syncthreads();
      if (tid == 0) {
        ws[Bn + bA] = GA + __logf((sredA[0] + sredA[1]) + (sredA[2] + sredA[3]));
        ws[Bn + bB] = GB + __logf((sredB[0] + sredB[1]) + (sredB[2] + sredB[3]));
      }
    }
  } else {
    // ==================== num pair (batches 2*(bid-16), +1) ====================
    const int nb = bid - 16;
    const int bA = 2 * nb, bB = bA + 1;
    const int LA = clampi(in_lens[bA], Sn, Tn);
    const int LB = clampi(in_lens[bB], Sn, Tn);
    const int Lm = LA > LB ? LA : LB;

    __shared__ float abuf[2][2][Sn + 3];  // [dbuf][batch][states at s+2]
    const float* lpA = logp + (size_t)bA * Tn * Cn;
    const float* lpB = logp + (size_t)bB * Tn * Cn;
    const int* tgA = targets + bA * Un;
    const int* tgB = targets + bB * Un;

    const int s1 = tid;        // states 0..255
    const int s2 = tid + 256;  // states 256..400 (valid if < Sn)
    int e1A = 0, e2A = 0, e1B = 0, e2B = 0;
    bool k1A = false, k2A = false, k1B = false, k2B = false;
    if (s1 & 1) {
      const int uu = (s1 - 1) >> 1;
      e1A = clampi(tgA[uu], 1, Cn - 1);
      e1B = clampi(tgB[uu], 1, Cn - 1);
      if (uu > 0) {
        k1A = (e1A != clampi(tgA[uu - 1], 1, Cn - 1));
        k1B = (e1B != clampi(tgB[uu - 1], 1, Cn - 1));
      }
    }
    if ((s2 < Sn) && (s2 & 1)) {
      const int uu = (s2 - 1) >> 1;
      e2A = clampi(tgA[uu], 1, Cn - 1);
      e2B = clampi(tgB[uu], 1, Cn - 1);
      k2A = (e2A != clampi(tgA[uu - 1], 1, Cn - 1));  // uu >= 127 > 0
      k2B = (e2B != clampi(tgB[uu - 1], 1, Cn - 1));
    }

    // t = 0 init (both batches)
    abuf[0][0][s1 + 2] = (s1 == 0) ? lpA[0] : (s1 == 1 ? lpA[e1A] : NEGF);
    abuf[0][1][s1 + 2] = (s1 == 0) ? lpB[0] : (s1 == 1 ? lpB[e1B] : NEGF);
    if (s2 < Sn) {
      abuf[0][0][s2 + 2] = NEGF;
      abuf[0][1][s2 + 2] = NEGF;
    }
    if (tid < 2) {
      abuf[0][0][tid] = NEGF;
      abuf[1][0][tid] = NEGF;
      abuf[0][1][tid] = NEGF;
      abuf[1][1][tid] = NEGF;
    }
    // 2-deep emission prefetch (addresses t-invariant per thread)
    float pe1A0 = lpA[Cn + e1A], pe2A0 = lpA[Cn + e2A];
    float pe1B0 = lpB[Cn + e1B], pe2B0 = lpB[Cn + e2B];
    float pe1A1 = lpA[(size_t)2 * Cn + e1A], pe2A1 = lpA[(size_t)2 * Cn + e2A];
    float pe1B1 = lpB[(size_t)2 * Cn + e1B], pe2B1 = lpB[(size_t)2 * Cn + e2B];
    __syncthreads();

    int cur = 0;
    for (int t = 1; t < Lm; ++t) {
      const float em1A = pe1A0, em2A = pe2A0, em1B = pe1B0, em2B = pe2B0;
      pe1A0 = pe1A1;
      pe2A0 = pe2A1;
      pe1B0 = pe1B1;
      pe2B0 = pe2B1;
      const int tpre = (t + 2 < Lm) ? t + 2 : Lm - 1;
      pe1A1 = lpA[(size_t)tpre * Cn + e1A];
      pe2A1 = lpA[(size_t)tpre * Cn + e2A];
      pe1B1 = lpB[(size_t)tpre * Cn + e1B];
      pe2B1 = lpB[(size_t)tpre * Cn + e2B];

      const float* AA = abuf[cur][0];
      const float* AB = abuf[cur][1];
      float* BvA = abuf[cur ^ 1][0];
      float* BvB = abuf[cur ^ 1][1];
      const bool liveA = (t < LA), liveB = (t < LB);
      {
        const float xA = AA[s1 + 2], yA = AA[s1 + 1];
        const float zA = k1A ? AA[s1] : NEGF;
        const float xB = AB[s1 + 2], yB = AB[s1 + 1];
        const float zB = k1B ? AB[s1] : NEGF;
        const float nvA = lse3(xA, yA, zA) + em1A;
        const float nvB = lse3(xB, yB, zB) + em1B;
        BvA[s1 + 2] = liveA ? nvA : xA;  // frozen: copy old forward
        BvB[s1 + 2] = liveB ? nvB : xB;
      }
      if (s2 < Sn) {
        const float xA = AA[s2 + 2], yA = AA[s2 + 1];
        const float zA = k2A ? AA[s2] : NEGF;
        const float xB = AB[s2 + 2], yB = AB[s2 + 1];
        const float zB = k2B ? AB[s2] : NEGF;
        const float nvA = lse3(xA, yA, zA) + em2A;
        const float nvB = lse3(xB, yB, zB) + em2B;
        BvA[s2 + 2] = liveA ? nvA : xA;
        BvB[s2 + 2] = liveB ? nvB : xB;
      }
      barrier_nodrain();
      cur ^= 1;
    }
    if (tid == 0) {
      {
        const int tl = clampi(tgt_lens[bA], 1, Un);
        const int l = 2 * tl;
        const float x = abuf[cur][0][l + 2], y = abuf[cur][0][l + 1];
        const float m = fmaxf(x, y);
        ws[bA] = m + __logf(__expf(x - m) + __expf(y - m));
      }
      {
        const int tl = clampi(tgt_lens[bB], 1, Un);
        const int l = 2 * tl;
        const float x = abuf[cur][1][l + 2], y = abuf[cur][1][l + 1];
        const float m = fmaxf(x, y);
        ws[bB] = m + __logf(__expf(x - m) + __expf(y - m));
      }
    }
  }
}

__global__ void finalize_kernel(const float* __restrict__ ws,
                                float* __restrict__ out) {
  const int tid = threadIdx.x;  // 64 threads, one wave
  float tot = 0.f, cnt = 0.f;
  if (tid < Bn) {
    const float tv = ws[tid] - ws[Bn + tid];  // num - DEN_SCALE*den
    const bool valid = tv > 0.5f * NEGF;
    tot = valid ? tv : 0.f;
    cnt = valid ? 1.f : 0.f;
  }
#pragma unroll
  for (int off = 32; off >= 1; off >>= 1) {
    tot += __shfl_xor(tot, off, 64);
    cnt += __shfl_xor(cnt, off, 64);
  }
  if (tid == 0) out[0] = -tot / fmaxf(cnt, 1.f);
}

extern "C" void kernel_launch(void* const* d_in, const int* in_sizes, int n_in,
                              void* d_out, int out_size, void* d_ws, size_t ws_size,
                              hipStream_t stream) {
  const float* logp = (const float*)d_in[0];
  const int* targets = (const int*)d_in[1];
  const int* in_lens = (const int*)d_in[2];
  const int* tgt_lens = (const int*)d_in[3];
  const float* trans = (const float*)d_in[4];
  const float* start = (const float*)d_in[5];
  float* ws = (float*)d_ws;
  float* out = (float*)d_out;
  (void)in_sizes; (void)n_in; (void)out_size; (void)ws_size;

  fwd_kernel<<<dim3(32), dim3(256), 0, stream>>>(
      logp, targets, in_lens, tgt_lens, trans, start, ws);
  finalize_kernel<<<dim3(1), dim3(64), 0, stream>>>(ws, out);
}